// Round 1
// baseline (367.908 us; speedup 1.0000x reference)
//
#include <hip/hip_runtime.h>
#include <hip/hip_bf16.h>
#include <math.h>

// Problem constants
#define BB 32
#define CI 64
#define CO 64
#define HH 128
#define WW 128
#define KK 4
#define HID 16

typedef __attribute__((ext_vector_type(8)))  __bf16 bf16x8;
typedef __attribute__((ext_vector_type(16))) float  floatx16;

__device__ __forceinline__ unsigned short f2bf(float f) {
    union { float f; unsigned int u; } a; a.f = f;
    unsigned int u = a.u;
    unsigned int r = (u + 0x7fffu + ((u >> 16) & 1u)) >> 16;  // RNE
    return (unsigned short)r;
}

// ---------------------------------------------------------------------------
// Kernel 1: fused pool + transpose/convert.
// Grid (H, B), block 256. Per block = one (b, y) row:
//   - read x[b][ic][y][:] fp32 (coalesced float4, 8 ic-rows per instr)
//   - write xT[b][y][c][ic] bf16 (ic-minor, uint4 stores, fully coalesced)
//   - emit rowsum[b][y][ic] = sum_c x  (attn finishes the mean)
// LDS transpose tile: [128 c][36 uint] (pad 36 -> 16B-aligned b128 reads,
// conflict-free read phase; write phase 4-way b32 = cheap).
// ---------------------------------------------------------------------------
__global__ __launch_bounds__(256) void pooltr_kernel(const float* __restrict__ x,
                                                     float* __restrict__ rowsum,
                                                     unsigned short* __restrict__ xT) {
    const int y = blockIdx.x;
    const int b = blockIdx.y;
    const int t = threadIdx.x;
    __shared__ __align__(16) unsigned int sT[128 * 36];

    const int ic2 = t >> 3;   // ic pair 0..31
    const int q   = t & 7;

    const float* xb = x + ((size_t)(b * CI + 2 * ic2) * HH + y) * WW;
    const float4* r0 = reinterpret_cast<const float4*>(xb);
    const float4* r1 = reinterpret_cast<const float4*>(xb + HH * WW);
    float s0 = 0.f, s1 = 0.f;
#pragma unroll
    for (int it = 0; it < 4; it++) {
        int c4 = q + it * 8;          // float4 col index 0..31
        float4 f0 = r0[c4];
        float4 f1 = r1[c4];
        s0 += f0.x + f0.y + f0.z + f0.w;
        s1 += f1.x + f1.y + f1.z + f1.w;
        int cb = c4 * 4;
        sT[(cb + 0) * 36 + ic2] = (unsigned)f2bf(f0.x) | ((unsigned)f2bf(f1.x) << 16);
        sT[(cb + 1) * 36 + ic2] = (unsigned)f2bf(f0.y) | ((unsigned)f2bf(f1.y) << 16);
        sT[(cb + 2) * 36 + ic2] = (unsigned)f2bf(f0.z) | ((unsigned)f2bf(f1.z) << 16);
        sT[(cb + 3) * 36 + ic2] = (unsigned)f2bf(f0.w) | ((unsigned)f2bf(f1.w) << 16);
    }
    // reduce row sums over the 8 col-threads (lanes q=0..7 within each group)
    s0 += __shfl_xor(s0, 1, 64); s1 += __shfl_xor(s1, 1, 64);
    s0 += __shfl_xor(s0, 2, 64); s1 += __shfl_xor(s1, 2, 64);
    s0 += __shfl_xor(s0, 4, 64); s1 += __shfl_xor(s1, 4, 64);
    if (q == 0) {
        *reinterpret_cast<float2*>(rowsum + ((size_t)b * HH + y) * CI + 2 * ic2) =
            make_float2(s0, s1);
    }
    __syncthreads();
    // write xT[b][y][c][ic] as uint4 (8 ic each)
    uint4* dst = reinterpret_cast<uint4*>(xT + ((size_t)b * HH + y) * (WW * CI));
#pragma unroll
    for (int jt = 0; jt < 4; jt++) {
        int idx = t + 256 * jt;       // 0..1023
        int c   = idx >> 3;
        int icq = idx & 7;
        dst[idx] = *reinterpret_cast<uint4*>(&sT[c * 36 + icq * 4]);
    }
}

// ---------------------------------------------------------------------------
// Kernel 2: finish pool (reduce rowsum over y) + attention MLP + 5 heads.
// 256 threads: waves parallelize the small head GEMVs.
// ---------------------------------------------------------------------------
__global__ __launch_bounds__(256) void attn_kernel(
    const float* __restrict__ rowsum,
    const float* __restrict__ mlp_w, const float* __restrict__ mlp_b,
    const float* __restrict__ wK, const float* __restrict__ bK,
    const float* __restrict__ wO, const float* __restrict__ bO,
    const float* __restrict__ wI, const float* __restrict__ bI,
    const float* __restrict__ wH, const float* __restrict__ bH,
    const float* __restrict__ wW, const float* __restrict__ bW,
    float* __restrict__ aK, float* __restrict__ aO, float* __restrict__ aI,
    float* __restrict__ aH, float* __restrict__ aW) {
    int b = blockIdx.x;
    int t = threadIdx.x;
    __shared__ float red[4][CI];
    __shared__ float sg[CI];
    __shared__ float sh[HID];
    __shared__ float sK[KK];
    __shared__ float sH[3];
    __shared__ float sW[3];

    {   // global average pool finish
        int ic = t & 63, seg = t >> 6;
        const float* rs = rowsum + (size_t)b * (HH * CI) + seg * 32 * CI + ic;
        float s = 0.f;
        for (int yy = 0; yy < 32; yy++) s += rs[yy * CI];
        red[seg][ic] = s;
    }
    __syncthreads();
    if (t < CI) sg[t] = (red[0][t] + red[1][t] + red[2][t] + red[3][t]) * (1.0f / (HH * WW));
    __syncthreads();

    if (t < HID) {
        float s = mlp_b[t];
        for (int c = 0; c < CI; c++) s = fmaf(mlp_w[t * CI + c], sg[c], s);
        sh[t] = fmaxf(s, 0.f);
    }
    __syncthreads();

    if (t < CO) {
        float sO = bO[t], sI = bI[t];
        for (int j = 0; j < HID; j++) {
            float hv = sh[j];
            sO = fmaf(wO[t * HID + j], hv, sO);
            sI = fmaf(wI[t * HID + j], hv, sI);
        }
        aO[b * CO + t] = 1.f / (1.f + expf(-sO));
        aI[b * CI + t] = 1.f / (1.f + expf(-sI));
    }
    if (t >= 64 && t < 64 + KK) {
        int u = t - 64;
        float s = bK[u];
        for (int j = 0; j < HID; j++) s = fmaf(wK[u * HID + j], sh[j], s);
        sK[u] = s;
    }
    if (t >= 128 && t < 131) {
        int u = t - 128;
        float s = bH[u];
        for (int j = 0; j < HID; j++) s = fmaf(wH[u * HID + j], sh[j], s);
        sH[u] = 1.f / (1.f + expf(-s));
        float s2 = bW[u];
        for (int j = 0; j < HID; j++) s2 = fmaf(wW[u * HID + j], sh[j], s2);
        sW[u] = 1.f / (1.f + expf(-s2));
    }
    __syncthreads();

    if (t == 0) {
        float m = fmaxf(fmaxf(sK[0], sK[1]), fmaxf(sK[2], sK[3]));
        float e0 = expf(sK[0] - m), e1 = expf(sK[1] - m);
        float e2 = expf(sK[2] - m), e3 = expf(sK[3] - m);
        float s = e0 + e1 + e2 + e3;
        aK[b * KK + 0] = e0 / s;
        aK[b * KK + 1] = e1 / s;
        aK[b * KK + 2] = e2 / s;
        aK[b * KK + 3] = e3 / s;
        float hs = sH[0] + sH[1] + sH[2] + 1e-6f;
        float wsum = sW[0] + sW[1] + sW[2] + 1e-6f;
        for (int i = 0; i < 3; i++) {
            aH[b * 3 + i] = sH[i] / hs;
            aW[b * 3 + i] = sW[i] / wsum;
        }
    }
}

// ---------------------------------------------------------------------------
// Kernel 3: dynamic weights -> bf16, layout wdbf[b][tap][oc][ic]  (unchanged)
// ---------------------------------------------------------------------------
#define WD_TOT (BB * 9 * CO * CI)
__global__ __launch_bounds__(256) void wdyn_kernel(
    const float* __restrict__ weight,
    const float* __restrict__ aK, const float* __restrict__ aO,
    const float* __restrict__ aI, const float* __restrict__ aH,
    const float* __restrict__ aW, unsigned short* __restrict__ wdbf) {
    int idx = blockIdx.x * 256 + threadIdx.x;
    if (idx >= WD_TOT) return;
    int i   = idx & 63;
    int o   = (idx >> 6) & 63;
    int bt  = idx >> 12;
    int tap = bt % 9;
    int b   = bt / 9;

    int wbase = (o * CI + i) * 9 + tap;
    const float* ak = aK + b * KK;
    float s = 0.f;
#pragma unroll
    for (int k = 0; k < KK; k++) s = fmaf(ak[k], weight[k * (CO * CI * 9) + wbase], s);
    float v = s * aO[b * CO + o] * aI[b * CI + i] *
              aH[b * 3 + tap / 3] * aW[b * 3 + tap % 3];
    wdbf[idx] = f2bf(v);
}

// ---------------------------------------------------------------------------
// Kernel 4: implicit-GEMM conv via v_mfma_f32_32x32x16_bf16.
// Staging now = pure b128 copies from pre-transposed bf16 xT[b][y][c][ic]
// with register prefetch of the next chunk overlapping the MFMA phase.
// LDS layouts (PADI=24 -> 48B stride, even bank-granule spread) unchanged.
// ---------------------------------------------------------------------------
#define ICCH 16
#define PADI 24
#define SX_ELE (6 * 130 * PADI)
#define SW_ELE (9 * 64 * PADI)
#define NXLD (6 * 130 * 2)   // 1560 uint4 per chunk (x tile)
#define NWLD (9 * 64 * 2)    // 1152 uint4 per chunk (weights)

__global__ __launch_bounds__(512, 4) void conv_kernel(
    const unsigned short* __restrict__ xT, const unsigned short* __restrict__ wdbf,
    const float* __restrict__ bias, float* __restrict__ out) {
    const int y0 = blockIdx.x * 4;
    const int b  = blockIdx.y;
    const int t  = threadIdx.x;
    const int lane = t & 63;
    const int w    = t >> 6;       // 0..7
    const int ry   = w >> 1;       // 0..3 output row within block
    const int c0   = (w & 1) * 64; // col half
    const int l31  = lane & 31;
    const int koct = lane >> 5;    // 0..1

    __shared__ __align__(16) unsigned short sx[SX_ELE];
    __shared__ __align__(16) unsigned short sw[SW_ELE];

    floatx16 acc[2][2];
#pragma unroll
    for (int i = 0; i < 2; i++)
#pragma unroll
        for (int j = 0; j < 2; j++)
#pragma unroll
            for (int q = 0; q < 16; q++) acc[i][j][q] = 0.f;

    const unsigned short* xb  = xT + (size_t)b * (HH * WW * CI);
    const unsigned short* wdb = wdbf + (size_t)b * (9 * CO * CI);

    // ---- precompute staging descriptors (chunk-independent) ----
    int xoff[4];   // ushort offset into xb, or -1 (halo zero)
    int sxoff[4];  // ushort offset into sx
#pragma unroll
    for (int j = 0; j < 4; j++) {
        int idx = t + 512 * j;
        xoff[j] = -1; sxoff[j] = 0;
        if (idx < NXLD) {
            int half = idx & 1, pix = idx >> 1;
            int r = pix / 130, c = pix - r * 130;
            int gy = y0 - 1 + r, gx = c - 1;
            sxoff[j] = pix * PADI + half * 8;
            if ((unsigned)gy < (unsigned)HH && (unsigned)gx < (unsigned)WW)
                xoff[j] = (gy * WW + gx) * CI + half * 8;
        }
    }
    int woff[3], swoff[3];
#pragma unroll
    for (int j = 0; j < 3; j++) {
        int idx = t + 512 * j;
        woff[j] = 0; swoff[j] = 0;
        if (idx < NWLD) {
            int k8 = idx & 1, oi = idx >> 1;   // oi = tap*64+oc
            woff[j]  = oi * 64 + k8 * 8;
            swoff[j] = oi * PADI + k8 * 8;
        }
    }

    uint4 vx[4], vw[3];
    auto issue = [&](int chunk) {
        const int co = chunk * ICCH;   // ushort offset advance per chunk
#pragma unroll
        for (int j = 0; j < 4; j++) {
            vx[j] = make_uint4(0u, 0u, 0u, 0u);
            if (xoff[j] >= 0)
                vx[j] = *reinterpret_cast<const uint4*>(xb + xoff[j] + co);
        }
#pragma unroll
        for (int j = 0; j < 3; j++) {
            if (t + 512 * j < NWLD)
                vw[j] = *reinterpret_cast<const uint4*>(wdb + woff[j] + co);
        }
    };
    auto commit = [&]() {
#pragma unroll
        for (int j = 0; j < 4; j++)
            if (t + 512 * j < NXLD)
                *reinterpret_cast<uint4*>(&sx[sxoff[j]]) = vx[j];
#pragma unroll
        for (int j = 0; j < 3; j++)
            if (t + 512 * j < NWLD)
                *reinterpret_cast<uint4*>(&sw[swoff[j]]) = vw[j];
    };

    // per-lane fragment base offsets (ushort units)
    const int pA0 = (0 * 32 + l31) * PADI + koct * 8;
    const int pA1 = (1 * 32 + l31) * PADI + koct * 8;
    const int pB0 = (ry * 130 + c0 + 0  + l31) * PADI + koct * 8;
    const int pB1 = (ry * 130 + c0 + 32 + l31) * PADI + koct * 8;

    issue(0);
    for (int chunk = 0; chunk < 4; chunk++) {
        __syncthreads();   // previous MFMA phase done -> LDS writable
        commit();
        __syncthreads();
        if (chunk < 3) issue(chunk + 1);   // overlap next loads with MFMA

        // ---- MFMA over 9 taps ----
#pragma unroll
        for (int kh = 0; kh < 3; kh++) {
#pragma unroll
            for (int kw = 0; kw < 3; kw++) {
                const int tap  = kh * 3 + kw;
                const int aoff = tap * (64 * PADI);
                const int boff = (kh * 130 + kw) * PADI;
                bf16x8 a0 = *reinterpret_cast<const bf16x8*>(&sw[pA0 + aoff]);
                bf16x8 a1 = *reinterpret_cast<const bf16x8*>(&sw[pA1 + aoff]);
                bf16x8 b0 = *reinterpret_cast<const bf16x8*>(&sx[pB0 + boff]);
                bf16x8 b1 = *reinterpret_cast<const bf16x8*>(&sx[pB1 + boff]);
                acc[0][0] = __builtin_amdgcn_mfma_f32_32x32x16_bf16(a0, b0, acc[0][0], 0, 0, 0);
                acc[0][1] = __builtin_amdgcn_mfma_f32_32x32x16_bf16(a0, b1, acc[0][1], 0, 0, 0);
                acc[1][0] = __builtin_amdgcn_mfma_f32_32x32x16_bf16(a1, b0, acc[1][0], 0, 0, 0);
                acc[1][1] = __builtin_amdgcn_mfma_f32_32x32x16_bf16(a1, b1, acc[1][1], 0, 0, 0);
            }
        }
    }

    // ---- epilogue: C/D map col=lane&31, row=(reg&3)+8*(reg>>2)+4*(lane>>5) ----
    const int y = y0 + ry;
    float* ob = out + (size_t)b * CO * HH * WW + (size_t)y * WW;
#pragma unroll
    for (int mt = 0; mt < 2; mt++) {
#pragma unroll
        for (int r = 0; r < 16; r++) {
            int oc = mt * 32 + (r & 3) + 8 * (r >> 2) + 4 * koct;
            float bv = bias[oc];
            ob[(size_t)oc * (HH * WW) + c0 + l31]      = acc[mt][0][r] + bv;
            ob[(size_t)oc * (HH * WW) + c0 + l31 + 32] = acc[mt][1][r] + bv;
        }
    }
}

// ---------------------------------------------------------------------------
extern "C" void kernel_launch(void* const* d_in, const int* in_sizes, int n_in,
                              void* d_out, int out_size, void* d_ws, size_t ws_size,
                              hipStream_t stream) {
    const float* x     = (const float*)d_in[0];
    const float* weight= (const float*)d_in[1];
    const float* bias  = (const float*)d_in[2];
    const float* mlp_w = (const float*)d_in[3];
    const float* mlp_b = (const float*)d_in[4];
    const float* wK    = (const float*)d_in[5];
    const float* bK    = (const float*)d_in[6];
    const float* wO    = (const float*)d_in[7];
    const float* bO    = (const float*)d_in[8];
    const float* wI    = (const float*)d_in[9];
    const float* bI    = (const float*)d_in[10];
    const float* wH    = (const float*)d_in[11];
    const float* bH    = (const float*)d_in[12];
    const float* wW    = (const float*)d_in[13];
    const float* bW    = (const float*)d_in[14];
    float* out = (float*)d_out;

    // workspace layout (floats):
    //   rowsum [32][128][64]           @ 0          (262144)
    //   aK[32*4] aO[32*64] aI[32*64]   @ 262144     (128+2048+2048)
    //   aH[32*3] aW[32*3]              @ 266368     (96+96)
    //   wdbf bf16 [32][9][64][64]      @ 266560     (589824 floats worth)
    //   xT   bf16 [32][128][128][64]   @ 856384     (67 MB)
    float* ws = (float*)d_ws;
    float* rowsum = ws;
    float* aK = ws + 262144;
    float* aO = aK + 128;
    float* aI = aO + 2048;
    float* aH = aI + 2048;
    float* aW = aH + 96;
    unsigned short* wdbf = (unsigned short*)(ws + 266560);
    unsigned short* xT   = (unsigned short*)(ws + 856384);

    pooltr_kernel<<<dim3(HH, BB), 256, 0, stream>>>(x, rowsum, xT);
    attn_kernel<<<BB, 256, 0, stream>>>(rowsum, mlp_w, mlp_b, wK, bK, wO, bO,
                                        wI, bI, wH, bH, wW, bW, aK, aO, aI, aH, aW);
    wdyn_kernel<<<(WD_TOT + 255) / 256, 256, 0, stream>>>(weight, aK, aO, aI, aH, aW, wdbf);
    conv_kernel<<<dim3(HH / 4, BB), 512, 0, stream>>>(xT, wdbf, bias, out);
}

// Round 3
// 321.750 us; speedup vs baseline: 1.1435x; 1.1435x over previous
//
#include <hip/hip_runtime.h>
#include <hip/hip_bf16.h>
#include <math.h>

// Problem constants
#define BB 32
#define CI 64
#define CO 64
#define HH 128
#define WW 128
#define KK 4
#define HID 16

typedef __attribute__((ext_vector_type(8)))  __bf16 bf16x8;
typedef __attribute__((ext_vector_type(16))) float  floatx16;

__device__ __forceinline__ unsigned short f2bf(float f) {
    union { float f; unsigned int u; } a; a.f = f;
    unsigned int u = a.u;
    unsigned int r = (u + 0x7fffu + ((u >> 16) & 1u)) >> 16;  // RNE
    return (unsigned short)r;
}

// ---------------------------------------------------------------------------
// Kernel 1: fused pool + transpose/convert.
// Grid (H, B), block 256. Per block = one (b, y) row:
//   - read x[b][ic][y][:] fp32 (coalesced float4, 8 ic-rows per instr)
//   - write xT chunk-major: xT[b][ch][y][c][16ic] bf16 (uint4, fully dense)
//   - emit rowsum[b][y][ic] = sum_c x  (attn finishes the mean)
// Chunk-major means conv's per-chunk staging reads are 100% line-dense
// (32B per pixel contiguous) instead of 32-of-128B slices.
// ---------------------------------------------------------------------------
__global__ __launch_bounds__(256) void pooltr_kernel(const float* __restrict__ x,
                                                     float* __restrict__ rowsum,
                                                     unsigned short* __restrict__ xT) {
    const int y = blockIdx.x;
    const int b = blockIdx.y;
    const int t = threadIdx.x;
    __shared__ __align__(16) unsigned int sT[128 * 36];

    const int ic2 = t >> 3;   // ic pair 0..31
    const int q   = t & 7;

    const float* xb = x + ((size_t)(b * CI + 2 * ic2) * HH + y) * WW;
    const float4* r0 = reinterpret_cast<const float4*>(xb);
    const float4* r1 = reinterpret_cast<const float4*>(xb + HH * WW);
    float s0 = 0.f, s1 = 0.f;
#pragma unroll
    for (int it = 0; it < 4; it++) {
        int c4 = q + it * 8;          // float4 col index 0..31
        float4 f0 = r0[c4];
        float4 f1 = r1[c4];
        s0 += f0.x + f0.y + f0.z + f0.w;
        s1 += f1.x + f1.y + f1.z + f1.w;
        int cb = c4 * 4;
        sT[(cb + 0) * 36 + ic2] = (unsigned)f2bf(f0.x) | ((unsigned)f2bf(f1.x) << 16);
        sT[(cb + 1) * 36 + ic2] = (unsigned)f2bf(f0.y) | ((unsigned)f2bf(f1.y) << 16);
        sT[(cb + 2) * 36 + ic2] = (unsigned)f2bf(f0.z) | ((unsigned)f2bf(f1.z) << 16);
        sT[(cb + 3) * 36 + ic2] = (unsigned)f2bf(f0.w) | ((unsigned)f2bf(f1.w) << 16);
    }
    // reduce row sums over the 8 col-threads
    s0 += __shfl_xor(s0, 1, 64); s1 += __shfl_xor(s1, 1, 64);
    s0 += __shfl_xor(s0, 2, 64); s1 += __shfl_xor(s1, 2, 64);
    s0 += __shfl_xor(s0, 4, 64); s1 += __shfl_xor(s1, 4, 64);
    if (q == 0) {
        *reinterpret_cast<float2*>(rowsum + ((size_t)b * HH + y) * CI + 2 * ic2) =
            make_float2(s0, s1);
    }
    __syncthreads();
    // write xT chunk-major: plane (b,ch) base + y row; uint4 = 8 ic (half-chunk)
#pragma unroll
    for (int jt = 0; jt < 4; jt++) {
        int idx = t + 256 * jt;       // 0..1023
        int p   = idx >> 8;           // chunk 0..3
        int r   = idx & 255;
        int c   = r >> 1;
        int h   = r & 1;
        uint4* dst = reinterpret_cast<uint4*>(
            xT + (((size_t)(b * 4 + p) * HH + y) * WW + c) * 16 + h * 8);
        *dst = *reinterpret_cast<uint4*>(&sT[c * 36 + p * 8 + h * 4]);
    }
}

// ---------------------------------------------------------------------------
// Kernel 2: finish pool (reduce rowsum over y) + attention MLP + 5 heads.
// ---------------------------------------------------------------------------
__global__ __launch_bounds__(256) void attn_kernel(
    const float* __restrict__ rowsum,
    const float* __restrict__ mlp_w, const float* __restrict__ mlp_b,
    const float* __restrict__ wK, const float* __restrict__ bK,
    const float* __restrict__ wO, const float* __restrict__ bO,
    const float* __restrict__ wI, const float* __restrict__ bI,
    const float* __restrict__ wH, const float* __restrict__ bH,
    const float* __restrict__ wW, const float* __restrict__ bW,
    float* __restrict__ aK, float* __restrict__ aO, float* __restrict__ aI,
    float* __restrict__ aH, float* __restrict__ aW) {
    int b = blockIdx.x;
    int t = threadIdx.x;
    __shared__ float red[4][CI];
    __shared__ float sg[CI];
    __shared__ float sh[HID];
    __shared__ float sK[KK];
    __shared__ float sH[3];
    __shared__ float sW[3];

    {   // global average pool finish
        int ic = t & 63, seg = t >> 6;
        const float* rs = rowsum + (size_t)b * (HH * CI) + seg * 32 * CI + ic;
        float s = 0.f;
        for (int yy = 0; yy < 32; yy++) s += rs[yy * CI];
        red[seg][ic] = s;
    }
    __syncthreads();
    if (t < CI) sg[t] = (red[0][t] + red[1][t] + red[2][t] + red[3][t]) * (1.0f / (HH * WW));
    __syncthreads();

    if (t < HID) {
        float s = mlp_b[t];
        for (int c = 0; c < CI; c++) s = fmaf(mlp_w[t * CI + c], sg[c], s);
        sh[t] = fmaxf(s, 0.f);
    }
    __syncthreads();

    if (t < CO) {
        float sO = bO[t], sI = bI[t];
        for (int j = 0; j < HID; j++) {
            float hv = sh[j];
            sO = fmaf(wO[t * HID + j], hv, sO);
            sI = fmaf(wI[t * HID + j], hv, sI);
        }
        aO[b * CO + t] = 1.f / (1.f + expf(-sO));
        aI[b * CI + t] = 1.f / (1.f + expf(-sI));
    }
    if (t >= 64 && t < 64 + KK) {
        int u = t - 64;
        float s = bK[u];
        for (int j = 0; j < HID; j++) s = fmaf(wK[u * HID + j], sh[j], s);
        sK[u] = s;
    }
    if (t >= 128 && t < 131) {
        int u = t - 128;
        float s = bH[u];
        for (int j = 0; j < HID; j++) s = fmaf(wH[u * HID + j], sh[j], s);
        sH[u] = 1.f / (1.f + expf(-s));
        float s2 = bW[u];
        for (int j = 0; j < HID; j++) s2 = fmaf(wW[u * HID + j], sh[j], s2);
        sW[u] = 1.f / (1.f + expf(-s2));
    }
    __syncthreads();

    if (t == 0) {
        float m = fmaxf(fmaxf(sK[0], sK[1]), fmaxf(sK[2], sK[3]));
        float e0 = expf(sK[0] - m), e1 = expf(sK[1] - m);
        float e2 = expf(sK[2] - m), e3 = expf(sK[3] - m);
        float s = e0 + e1 + e2 + e3;
        aK[b * KK + 0] = e0 / s;
        aK[b * KK + 1] = e1 / s;
        aK[b * KK + 2] = e2 / s;
        aK[b * KK + 3] = e3 / s;
        float hs = sH[0] + sH[1] + sH[2] + 1e-6f;
        float wsum = sW[0] + sW[1] + sW[2] + 1e-6f;
        for (int i = 0; i < 3; i++) {
            aH[b * 3 + i] = sH[i] / hs;
            aW[b * 3 + i] = sW[i] / wsum;
        }
    }
}

// ---------------------------------------------------------------------------
// Kernel 3: dynamic weights -> bf16, chunk-major: wdbf[b][ch][tap][oc][16ic]
// ---------------------------------------------------------------------------
#define WD_TOT (BB * 9 * CO * CI)
__global__ __launch_bounds__(256) void wdyn_kernel(
    const float* __restrict__ weight,
    const float* __restrict__ aK, const float* __restrict__ aO,
    const float* __restrict__ aI, const float* __restrict__ aH,
    const float* __restrict__ aW, unsigned short* __restrict__ wdbf) {
    int idx = blockIdx.x * 256 + threadIdx.x;
    if (idx >= WD_TOT) return;
    int i   = idx & 63;
    int o   = (idx >> 6) & 63;
    int bt  = idx >> 12;
    int tap = bt % 9;
    int b   = bt / 9;

    int wbase = (o * CI + i) * 9 + tap;
    const float* ak = aK + b * KK;
    float s = 0.f;
#pragma unroll
    for (int k = 0; k < KK; k++) s = fmaf(ak[k], weight[k * (CO * CI * 9) + wbase], s);
    float v = s * aO[b * CO + o] * aI[b * CI + i] *
              aH[b * 3 + tap / 3] * aW[b * 3 + tap % 3];
    // chunk-major store
    int ch = i >> 4, icw = i & 15;
    wdbf[(((size_t)(b * 4 + ch) * 9 + tap) * CO + o) * 16 + icw] = f2bf(v);
}

// ---------------------------------------------------------------------------
// Kernel 4: implicit-GEMM conv via v_mfma_f32_32x32x16_bf16.
// Staging = dense b128 copies from chunk-major xT / wdbf, register prefetch
// of the next chunk overlapping the MFMA phase. LDS layouts unchanged.
// ---------------------------------------------------------------------------
#define ICCH 16
#define PADI 24
#define SX_ELE (6 * 130 * PADI)
#define SW_ELE (9 * 64 * PADI)
#define NXLD (6 * 130 * 2)     // 1560 uint4 per chunk (x tile)
#define NWLD (9 * 64 * 2)      // 1152 uint4 per chunk (weights)
#define XPLANE (HH * WW * 16)  // ushorts per (b,chunk) x plane
#define WPLANE (9 * 64 * 16)   // ushorts per (b,chunk) weight plane

__global__ __launch_bounds__(512, 4) void conv_kernel(
    const unsigned short* __restrict__ xT, const unsigned short* __restrict__ wdbf,
    const float* __restrict__ bias, float* __restrict__ out) {
    const int y0 = blockIdx.x * 4;
    const int b  = blockIdx.y;
    const int t  = threadIdx.x;
    const int lane = t & 63;
    const int w    = t >> 6;       // 0..7
    const int ry   = w >> 1;       // 0..3 output row within block
    const int c0   = (w & 1) * 64; // col half
    const int l31  = lane & 31;
    const int koct = lane >> 5;    // 0..1

    __shared__ __align__(16) unsigned short sx[SX_ELE];
    __shared__ __align__(16) unsigned short sw[SW_ELE];

    floatx16 acc[2][2];
#pragma unroll
    for (int i = 0; i < 2; i++)
#pragma unroll
        for (int j = 0; j < 2; j++)
#pragma unroll
            for (int q = 0; q < 16; q++) acc[i][j][q] = 0.f;

    const unsigned short* xb  = xT + (size_t)b * (4 * XPLANE);
    const unsigned short* wdb = wdbf + (size_t)b * (4 * WPLANE);

    // ---- staging descriptors (chunk advance = plane stride) ----
    int xoff[4];   // ushort offset into x plane, or -1 (halo zero)
    int sxoff[4];  // ushort offset into sx
#pragma unroll
    for (int j = 0; j < 4; j++) {
        int idx = t + 512 * j;
        xoff[j] = -1; sxoff[j] = 0;
        if (idx < NXLD) {
            int half = idx & 1, pix = idx >> 1;
            int r = pix / 130, c = pix - r * 130;
            int gy = y0 - 1 + r, gx = c - 1;
            sxoff[j] = pix * PADI + half * 8;
            if ((unsigned)gy < (unsigned)HH && (unsigned)gx < (unsigned)WW)
                xoff[j] = (gy * WW + gx) * 16 + half * 8;
        }
    }
    int woff[3], swoff[3];
#pragma unroll
    for (int j = 0; j < 3; j++) {
        int idx = t + 512 * j;
        woff[j] = 0; swoff[j] = 0;
        if (idx < NWLD) {
            int k8 = idx & 1, oi = idx >> 1;   // oi = tap*64+oc
            woff[j]  = oi * 16 + k8 * 8;
            swoff[j] = oi * PADI + k8 * 8;
        }
    }

    uint4 vx[4], vw[3];
    auto issue = [&](int chunk) {
        const unsigned short* xp = xb + (size_t)chunk * XPLANE;
        const unsigned short* wp = wdb + (size_t)chunk * WPLANE;
#pragma unroll
        for (int j = 0; j < 4; j++) {
            vx[j] = make_uint4(0u, 0u, 0u, 0u);
            if (xoff[j] >= 0)
                vx[j] = *reinterpret_cast<const uint4*>(xp + xoff[j]);
        }
#pragma unroll
        for (int j = 0; j < 3; j++) {
            if (t + 512 * j < NWLD)
                vw[j] = *reinterpret_cast<const uint4*>(wp + woff[j]);
        }
    };
    auto commit = [&]() {
#pragma unroll
        for (int j = 0; j < 4; j++)
            if (t + 512 * j < NXLD)
                *reinterpret_cast<uint4*>(&sx[sxoff[j]]) = vx[j];
#pragma unroll
        for (int j = 0; j < 3; j++)
            if (t + 512 * j < NWLD)
                *reinterpret_cast<uint4*>(&sw[swoff[j]]) = vw[j];
    };

    // per-lane fragment base offsets (ushort units)
    const int pA0 = (0 * 32 + l31) * PADI + koct * 8;
    const int pA1 = (1 * 32 + l31) * PADI + koct * 8;
    const int pB0 = (ry * 130 + c0 + 0  + l31) * PADI + koct * 8;
    const int pB1 = (ry * 130 + c0 + 32 + l31) * PADI + koct * 8;

    issue(0);
    for (int chunk = 0; chunk < 4; chunk++) {
        __syncthreads();   // previous MFMA phase done -> LDS writable
        commit();
        __syncthreads();
        if (chunk < 3) issue(chunk + 1);   // overlap next loads with MFMA

        // ---- MFMA over 9 taps ----
#pragma unroll
        for (int kh = 0; kh < 3; kh++) {
#pragma unroll
            for (int kw = 0; kw < 3; kw++) {
                const int tap  = kh * 3 + kw;
                const int aoff = tap * (64 * PADI);
                const int boff = (kh * 130 + kw) * PADI;
                bf16x8 a0 = *reinterpret_cast<const bf16x8*>(&sw[pA0 + aoff]);
                bf16x8 a1 = *reinterpret_cast<const bf16x8*>(&sw[pA1 + aoff]);
                bf16x8 b0 = *reinterpret_cast<const bf16x8*>(&sx[pB0 + boff]);
                bf16x8 b1 = *reinterpret_cast<const bf16x8*>(&sx[pB1 + boff]);
                acc[0][0] = __builtin_amdgcn_mfma_f32_32x32x16_bf16(a0, b0, acc[0][0], 0, 0, 0);
                acc[0][1] = __builtin_amdgcn_mfma_f32_32x32x16_bf16(a0, b1, acc[0][1], 0, 0, 0);
                acc[1][0] = __builtin_amdgcn_mfma_f32_32x32x16_bf16(a1, b0, acc[1][0], 0, 0, 0);
                acc[1][1] = __builtin_amdgcn_mfma_f32_32x32x16_bf16(a1, b1, acc[1][1], 0, 0, 0);
            }
        }
    }

    // ---- epilogue: C/D map col=lane&31, row=(reg&3)+8*(reg>>2)+4*(lane>>5) ----
    const int y = y0 + ry;
    float* ob = out + (size_t)b * CO * HH * WW + (size_t)y * WW;
#pragma unroll
    for (int mt = 0; mt < 2; mt++) {
#pragma unroll
        for (int r = 0; r < 16; r++) {
            int oc = mt * 32 + (r & 3) + 8 * (r >> 2) + 4 * koct;
            float bv = bias[oc];
            ob[(size_t)oc * (HH * WW) + c0 + l31]      = acc[mt][0][r] + bv;
            ob[(size_t)oc * (HH * WW) + c0 + l31 + 32] = acc[mt][1][r] + bv;
        }
    }
}

// ---------------------------------------------------------------------------
extern "C" void kernel_launch(void* const* d_in, const int* in_sizes, int n_in,
                              void* d_out, int out_size, void* d_ws, size_t ws_size,
                              hipStream_t stream) {
    const float* x     = (const float*)d_in[0];
    const float* weight= (const float*)d_in[1];
    const float* bias  = (const float*)d_in[2];
    const float* mlp_w = (const float*)d_in[3];
    const float* mlp_b = (const float*)d_in[4];
    const float* wK    = (const float*)d_in[5];
    const float* bK    = (const float*)d_in[6];
    const float* wO    = (const float*)d_in[7];
    const float* bO    = (const float*)d_in[8];
    const float* wI    = (const float*)d_in[9];
    const float* bI    = (const float*)d_in[10];
    const float* wH    = (const float*)d_in[11];
    const float* bH    = (const float*)d_in[12];
    const float* wW    = (const float*)d_in[13];
    const float* bW    = (const float*)d_in[14];
    float* out = (float*)d_out;

    // workspace layout (floats):
    //   rowsum [32][128][64]           @ 0          (262144)
    //   aK aO aI aH aW                 @ 262144
    //   wdbf bf16 [32][4][9][64][16]   @ 266560
    //   xT   bf16 [32][4][128][128][16]@ 856384     (67 MB)
    float* ws = (float*)d_ws;
    float* rowsum = ws;
    float* aK = ws + 262144;
    float* aO = aK + 128;
    float* aI = aO + 2048;
    float* aH = aI + 2048;
    float* aW = aH + 96;
    unsigned short* wdbf = (unsigned short*)(ws + 266560);
    unsigned short* xT   = (unsigned short*)(ws + 856384);

    pooltr_kernel<<<dim3(HH, BB), 256, 0, stream>>>(x, rowsum, xT);
    attn_kernel<<<BB, 256, 0, stream>>>(rowsum, mlp_w, mlp_b, wK, bK, wO, bO,
                                        wI, bI, wH, bH, wW, bW, aK, aO, aI, aH, aW);
    wdyn_kernel<<<(WD_TOT + 255) / 256, 256, 0, stream>>>(weight, aK, aO, aI, aH, aW, wdbf);
    conv_kernel<<<dim3(HH / 4, BB), 512, 0, stream>>>(xT, wdbf, bias, out);
}